// Round 1
// baseline (538.098 us; speedup 1.0000x reference)
//
#include <hip/hip_runtime.h>

typedef unsigned char  u8;
typedef unsigned short u16;
typedef unsigned int   u32;

typedef __attribute__((ext_vector_type(8))) short bf16x8;
typedef __attribute__((ext_vector_type(4))) float f32x4;

__device__ __forceinline__ u16 f2bf(float f) {
  union { float f; u32 u; } v; v.f = f;
  u32 u = v.u;
  u32 r = u + 0x7fffu + ((u >> 16) & 1u);
  return (u16)(r >> 16);
}
__device__ __forceinline__ float bf2f(u16 h) {
  union { u32 u; float f; } v; v.u = ((u32)h) << 16;
  return v.f;
}
__device__ __forceinline__ bf16x8 pack8(float4 a, float4 b) {
  bf16x8 r;
  r[0] = (short)f2bf(a.x); r[1] = (short)f2bf(a.y);
  r[2] = (short)f2bf(a.z); r[3] = (short)f2bf(a.w);
  r[4] = (short)f2bf(b.x); r[5] = (short)f2bf(b.y);
  r[6] = (short)f2bf(b.z); r[7] = (short)f2bf(b.w);
  return r;
}
__device__ __forceinline__ f32x4 mfma16(bf16x8 a, bf16x8 b, f32x4 c) {
  return __builtin_amdgcn_mfma_f32_16x16x32_bf16(a, b, c, 0, 0, 0);
}

// ---------------- mask dtype detection + conversion ----------------
__global__ void kflaginit(u32* flags) { flags[0] = 0; flags[1] = 0; }

__global__ void kscan(const u32* __restrict__ m, u32* __restrict__ flags) {
  int gid = blockIdx.x * 256 + threadIdx.x;   // 262144 threads
  const uint4* p = (const uint4*)m;
  u32 gt = 0, fp = 0;
#pragma unroll
  for (int i = 0; i < 4; ++i) {
    uint4 v = p[gid * 4 + i];                 // covers first 4M words = 16MB (safe for all dtypes)
    gt |= (u32)((v.x > 1u) | (v.y > 1u) | (v.z > 1u) | (v.w > 1u));
    fp |= (u32)((v.x == 0x3F800000u) | (v.y == 0x3F800000u) |
                (v.z == 0x3F800000u) | (v.w == 0x3F800000u));
  }
  if (gt) flags[0] = 1;
  if (fp) flags[1] = 1;
}

__global__ void kconv(const void* __restrict__ m, const u32* __restrict__ flags,
                      u8* __restrict__ out) {
  int gid = blockIdx.x * 256 + threadIdx.x;   // quad index < 8388608
  u32 isf = flags[1], isb = flags[0];
  uchar4 o;
  if (isf) {            // fp32 0/1 mask
    float4 v = ((const float4*)m)[gid];
    o.x = v.x != 0.f; o.y = v.y != 0.f; o.z = v.z != 0.f; o.w = v.w != 0.f;
  } else if (isb) {     // byte (bool) mask
    uchar4 v = ((const uchar4*)m)[gid];
    o.x = v.x != 0; o.y = v.y != 0; o.z = v.z != 0; o.w = v.w != 0;
  } else {              // int32 0/1 mask
    uint4 v = ((const uint4*)m)[gid];
    o.x = v.x != 0; o.y = v.y != 0; o.z = v.z != 0; o.w = v.w != 0;
  }
  ((uchar4*)out)[gid] = o;
}

// ---------------- per-batch scalar gates ----------------
__global__ void kgates(const float* __restrict__ iu,
                       const float* __restrict__ q1, const float* __restrict__ q2,
                       const float* __restrict__ k1, const float* __restrict__ k2,
                       const float* __restrict__ v1, const float* __restrict__ v2,
                       float* __restrict__ gates) {
  int b = blockIdx.x, t = threadIdx.x;
  __shared__ float u[64];
  u[t] = iu[b * 64 + t];
  __syncthreads();
  const float* w1[3] = {q1, k1, v1};
  const float* w2[3] = {q2, k2, v2};
#pragma unroll
  for (int m = 0; m < 3; ++m) {
    float p = 0.f;
    if (t < 32) {
      float h = 0.f;
      for (int i = 0; i < 64; ++i) h += u[i] * w1[m][i * 32 + t];
      h = fmaxf(h, 0.f);
      p = h * w2[m][t];
    }
    for (int off = 32; off >= 1; off >>= 1) p += __shfl_xor(p, off);
    if (t == 0) gates[m * 128 + b] = p;
  }
}

// ---------------- Q/K projections (scale folded; u-parts shared) ----------------
__launch_bounds__(256, 1)
__global__ void kproj_qk(const float* __restrict__ x,
                         const float* __restrict__ wq, const float* __restrict__ uq,
                         const float* __restrict__ wk, const float* __restrict__ uk,
                         const float* __restrict__ gates,
                         u16* __restrict__ qc, u16* __restrict__ qu,
                         u16* __restrict__ kc, u16* __restrict__ ku) {
  __shared__ u16 XT[64 * 136];
  __shared__ u16 WT[640 * 72];
  int b = blockIdx.x >> 3, l0 = (blockIdx.x & 7) * 64, t = threadIdx.x;
  {
    int tok = t >> 2, i0 = (t & 3) * 16;
    const float4* s = (const float4*)(x + ((size_t)(b * 512 + l0 + tok)) * 64 + i0);
    *(bf16x8*)&XT[tok * 136 + i0]     = pack8(s[0], s[1]);
    *(bf16x8*)&XT[tok * 136 + i0 + 8] = pack8(s[2], s[3]);
  }
  for (int i = 0; i < 64; ++i) { int e = t + i * 256; WT[(e & 255) * 72 + (e >> 8)] = (short)f2bf(wq[e]); }
  for (int i = 0; i < 16; ++i) { int e = t + i * 256; WT[(256 + (e & 63)) * 72 + (e >> 6)] = (short)f2bf(uq[e]); }
  for (int i = 0; i < 64; ++i) { int e = t + i * 256; WT[(320 + (e & 255)) * 72 + (e >> 8)] = (short)f2bf(wk[e]); }
  for (int i = 0; i < 16; ++i) { int e = t + i * 256; WT[(576 + (e & 63)) * 72 + (e >> 6)] = (short)f2bf(uk[e]); }
  __syncthreads();

  int w = t >> 6, lane = t & 63, lrow = lane & 15, lgrp = lane >> 4;
  bf16x8 af[4][2];
#pragma unroll
  for (int m = 0; m < 4; ++m)
#pragma unroll
    for (int fs = 0; fs < 2; ++fs)
      af[m][fs] = *(const bf16x8*)&XT[(m * 16 + lrow) * 136 + fs * 32 + lgrp * 8];

  float sq = gates[b], sk = gates[128 + b];
  const f32x4 fz = {0.f, 0.f, 0.f, 0.f};
#pragma unroll
  for (int part = 0; part < 2; ++part) {
    f32x4 acc[4][5];
#pragma unroll
    for (int m = 0; m < 4; ++m)
#pragma unroll
      for (int nt = 0; nt < 5; ++nt) acc[m][nt] = fz;
#pragma unroll
    for (int fs = 0; fs < 2; ++fs)
#pragma unroll
      for (int nt = 0; nt < 5; ++nt) {
        bf16x8 bf = *(const bf16x8*)&WT[(part * 320 + w * 80 + nt * 16 + lrow) * 72 + fs * 32 + lgrp * 8];
#pragma unroll
        for (int m = 0; m < 4; ++m)
          acc[m][nt] = mfma16(af[m][fs], bf, acc[m][nt]);
      }
    u16* dstC = part ? kc : qc;
    u16* dstU = part ? ku : qu;
    float presc = part ? 1.0f : 0.125f;
    float g = (part ? sk : sq) * presc;
#pragma unroll
    for (int nt = 0; nt < 5; ++nt) {
      int ncol = w * 80 + nt * 16 + lrow;
#pragma unroll
      for (int m = 0; m < 4; ++m)
#pragma unroll
        for (int j = 0; j < 4; ++j) {
          int l = l0 + m * 16 + lgrp * 4 + j;
          float v = acc[m][nt][j];
          if (ncol < 256) {
            dstC[(((size_t)(b * 4 + (ncol >> 6)) * 512) + l) * 64 + (ncol & 63)] = (short)f2bf(v * presc);
          } else {
            dstU[((size_t)b * 512 + l) * 64 + (ncol - 256)] = (short)f2bf(v * g);
          }
        }
    }
  }
}

// ---------------- V projection, gated u_V add, transposed store ----------------
__launch_bounds__(256, 1)
__global__ void kproj_v(const float* __restrict__ x,
                        const float* __restrict__ wv, const float* __restrict__ uv,
                        const float* __restrict__ gates, u16* __restrict__ vpt) {
  __shared__ u16 XT[64 * 136];
  __shared__ u16 WT[320 * 72];
  __shared__ float Vs[64 * 328];
  int b = blockIdx.x >> 3, l0 = (blockIdx.x & 7) * 64, t = threadIdx.x;
  {
    int tok = t >> 2, i0 = (t & 3) * 16;
    const float4* s = (const float4*)(x + ((size_t)(b * 512 + l0 + tok)) * 64 + i0);
    *(bf16x8*)&XT[tok * 136 + i0]     = pack8(s[0], s[1]);
    *(bf16x8*)&XT[tok * 136 + i0 + 8] = pack8(s[2], s[3]);
  }
  for (int i = 0; i < 64; ++i) { int e = t + i * 256; WT[(e & 255) * 72 + (e >> 8)] = (short)f2bf(wv[e]); }
  for (int i = 0; i < 16; ++i) { int e = t + i * 256; WT[(256 + (e & 63)) * 72 + (e >> 6)] = (short)f2bf(uv[e]); }
  __syncthreads();

  int w = t >> 6, lane = t & 63, lrow = lane & 15, lgrp = lane >> 4;
  bf16x8 af[4][2];
#pragma unroll
  for (int m = 0; m < 4; ++m)
#pragma unroll
    for (int fs = 0; fs < 2; ++fs)
      af[m][fs] = *(const bf16x8*)&XT[(m * 16 + lrow) * 136 + fs * 32 + lgrp * 8];

  const f32x4 fz = {0.f, 0.f, 0.f, 0.f};
  f32x4 acc[4][5];
#pragma unroll
  for (int m = 0; m < 4; ++m)
#pragma unroll
    for (int nt = 0; nt < 5; ++nt) acc[m][nt] = fz;
#pragma unroll
  for (int fs = 0; fs < 2; ++fs)
#pragma unroll
    for (int nt = 0; nt < 5; ++nt) {
      bf16x8 bf = *(const bf16x8*)&WT[(w * 80 + nt * 16 + lrow) * 72 + fs * 32 + lgrp * 8];
#pragma unroll
      for (int m = 0; m < 4; ++m)
        acc[m][nt] = mfma16(af[m][fs], bf, acc[m][nt]);
    }
#pragma unroll
  for (int nt = 0; nt < 5; ++nt)
#pragma unroll
    for (int m = 0; m < 4; ++m)
#pragma unroll
      for (int j = 0; j < 4; ++j)
        Vs[(m * 16 + lgrp * 4 + j) * 328 + w * 80 + nt * 16 + lrow] = acc[m][nt][j];
  __syncthreads();

  float sv = gates[256 + b];
#pragma unroll
  for (int p = 0; p < 4; ++p) {
    int hd = p * 64 + (t >> 2);
    int d = hd & 63;
    int tok0 = (t & 3) * 16;
    bf16x8 v0, v1;
#pragma unroll
    for (int i = 0; i < 8; ++i) {
      int tok = tok0 + i;
      v0[i] = (short)f2bf(Vs[tok * 328 + hd] + Vs[tok * 328 + 256 + d] * sv);
    }
#pragma unroll
    for (int i = 0; i < 8; ++i) {
      int tok = tok0 + 8 + i;
      v1[i] = (short)f2bf(Vs[tok * 328 + hd] + Vs[tok * 328 + 256 + d] * sv);
    }
    size_t base = (((size_t)(b * 4 + (hd >> 6)) * 64) + d) * 512 + l0 + tok0;
    *(bf16x8*)&vpt[base] = v0;
    *(bf16x8*)&vpt[base + 8] = v1;
  }
}

// ---------------- fused attention: scores -> softmax -> attn write -> P.V ----------------
__launch_bounds__(256, 1)
__global__ void kattn(const u16* __restrict__ qc, const u16* __restrict__ qu,
                      const u16* __restrict__ kc, const u16* __restrict__ ku,
                      const u16* __restrict__ vpt, const u8* __restrict__ maskb,
                      float* __restrict__ aout, u16* __restrict__ ctx) {
  __shared__ char smem[133120];
  u16* QT = (u16*)smem;                 // phase1: [64][136]
  u16* KT = (u16*)(smem + 17408);       // phase1: [128][136]
  u16* Pl = (u16*)smem;                 // phase2: [64][520]
  u16* Vt = (u16*)(smem + 66560);       // [64][520]

  int bid = blockIdx.x;
  int bh = bid >> 3, qt = bid & 7;
  int b = bh >> 2, hh = bh & 3;
  int q0 = qt * 64;
  int t = threadIdx.x, w = t >> 6, lane = t & 63, lrow = lane & 15, lgrp = lane >> 4;

  { // stage Q tile: [0:64]=Q (per head), [64:128]=uQ (shared)
    int tok = t >> 2, c0 = (t & 3) * 32;
    const u16* src = (c0 < 64)
      ? qc + ((size_t)bh * 512 + q0 + tok) * 64 + c0
      : qu + ((size_t)b  * 512 + q0 + tok) * 64 + (c0 - 64);
#pragma unroll
    for (int i = 0; i < 4; ++i)
      *(bf16x8*)&QT[tok * 136 + c0 + i * 8] = *(const bf16x8*)&src[i * 8];
  }
  { // stage Vp^T tile [64 d][512 l]
    int d = t >> 2, c0 = (t & 3) * 128;
    const u16* src = vpt + ((size_t)bh * 64 + d) * 512 + c0;
#pragma unroll
    for (int i = 0; i < 16; ++i)
      *(bf16x8*)&Vt[d * 520 + c0 + i * 8] = *(const bf16x8*)&src[i * 8];
  }

  const f32x4 fz = {0.f, 0.f, 0.f, 0.f};
  f32x4 sacc[32];
#pragma unroll
  for (int i = 0; i < 32; ++i) sacc[i] = fz;

#pragma unroll
  for (int kt = 0; kt < 4; ++kt) {
    __syncthreads();
    { // stage K tile rows kt*128..+128: [0:64]=K, [64:128]=uK
      int r = t >> 1, c0 = (t & 1) * 64;
      const u16* src = (c0 == 0)
        ? kc + ((size_t)bh * 512 + kt * 128 + r) * 64
        : ku + ((size_t)b  * 512 + kt * 128 + r) * 64;
#pragma unroll
      for (int i = 0; i < 8; ++i)
        *(bf16x8*)&KT[r * 136 + c0 + i * 8] = *(const bf16x8*)&src[i * 8];
    }
    __syncthreads();
#pragma unroll
    for (int fs = 0; fs < 4; ++fs) {
      bf16x8 a = *(const bf16x8*)&QT[(w * 16 + lrow) * 136 + fs * 32 + lgrp * 8];
#pragma unroll
      for (int nt = 0; nt < 8; ++nt) {
        bf16x8 bf = *(const bf16x8*)&KT[(nt * 16 + lrow) * 136 + fs * 32 + lgrp * 8];
        sacc[kt * 8 + nt] = mfma16(a, bf, sacc[kt * 8 + nt]);
      }
    }
  }
  __syncthreads();   // KT reads done (P overlaps); Vt staged & visible

  // mask + exact softmax (rows live in-register: 16 lanes x 32 in-lane vals)
  int qloc0 = w * 16 + lgrp * 4;
  const u8* mrow = maskb + ((size_t)b * 512 + q0 + qloc0) * 512;
  float mj[4] = {-3.0e38f, -3.0e38f, -3.0e38f, -3.0e38f};
#pragma unroll
  for (int i = 0; i < 32; ++i) {
    int kpos = (i >> 3) * 128 + (i & 7) * 16 + lrow;
#pragma unroll
    for (int j = 0; j < 4; ++j) {
      float s = sacc[i][j];
      if (mrow[(size_t)j * 512 + kpos]) s = -1.0e9f;
      sacc[i][j] = s;
      mj[j] = fmaxf(mj[j], s);
    }
  }
#pragma unroll
  for (int j = 0; j < 4; ++j) {
    mj[j] = fmaxf(mj[j], __shfl_xor(mj[j], 1));
    mj[j] = fmaxf(mj[j], __shfl_xor(mj[j], 2));
    mj[j] = fmaxf(mj[j], __shfl_xor(mj[j], 4));
    mj[j] = fmaxf(mj[j], __shfl_xor(mj[j], 8));
  }
  float lj[4] = {0.f, 0.f, 0.f, 0.f};
#pragma unroll
  for (int i = 0; i < 32; ++i)
#pragma unroll
    for (int j = 0; j < 4; ++j) {
      float p = __expf(sacc[i][j] - mj[j]);
      sacc[i][j] = p;
      lj[j] += p;
    }
#pragma unroll
  for (int j = 0; j < 4; ++j) {
    lj[j] += __shfl_xor(lj[j], 1);
    lj[j] += __shfl_xor(lj[j], 2);
    lj[j] += __shfl_xor(lj[j], 4);
    lj[j] += __shfl_xor(lj[j], 8);
  }
  float inv[4];
#pragma unroll
  for (int j = 0; j < 4; ++j) inv[j] = 1.0f / lj[j];

  size_t ab = ((size_t)bh * 512 + q0 + qloc0) * 512;
#pragma unroll
  for (int i = 0; i < 32; ++i) {
    int kpos = (i >> 3) * 128 + (i & 7) * 16 + lrow;
#pragma unroll
    for (int j = 0; j < 4; ++j) {
      float aval = sacc[i][j] * inv[j];
      aout[ab + (size_t)j * 512 + kpos] = aval;
      Pl[(qloc0 + j) * 520 + kpos] = (short)f2bf(aval);
    }
  }

  // phase 2: context = P @ Vp  (A rows own-wave, no extra barrier needed)
  f32x4 cacc[4];
#pragma unroll
  for (int nt = 0; nt < 4; ++nt) cacc[nt] = fz;
#pragma unroll
  for (int ks = 0; ks < 16; ++ks) {
    bf16x8 a = *(const bf16x8*)&Pl[(w * 16 + lrow) * 520 + ks * 32 + lgrp * 8];
#pragma unroll
    for (int nt = 0; nt < 4; ++nt) {
      bf16x8 bf = *(const bf16x8*)&Vt[(nt * 16 + lrow) * 520 + ks * 32 + lgrp * 8];
      cacc[nt] = mfma16(a, bf, cacc[nt]);
    }
  }
#pragma unroll
  for (int nt = 0; nt < 4; ++nt)
#pragma unroll
    for (int j = 0; j < 4; ++j) {
      int q = q0 + qloc0 + j;
      ctx[((size_t)b * 512 + q) * 256 + hh * 64 + nt * 16 + lrow] = (short)f2bf(cacc[nt][j]);
    }
}

// ---------------- fc + residual + LN + FFN + residual + LN ----------------
__launch_bounds__(256, 1)
__global__ void kffn(const u16* __restrict__ ctx, const float* __restrict__ x,
                     const float* __restrict__ fcw, const float* __restrict__ f1w,
                     const float* __restrict__ f2w, float* __restrict__ out) {
  __shared__ u16 CT[64 * 264];
  __shared__ u16 FCT[64 * 264];
  __shared__ u16 F1T[64 * 72];
  __shared__ u16 F2T[64 * 72];
  __shared__ float ENC[64 * 68];
  __shared__ u16 EBF[64 * 72];
  __shared__ u16 HBF[64 * 72];
  int b = blockIdx.x >> 3, l0 = (blockIdx.x & 7) * 64, t = threadIdx.x;
  {
    int tok = t >> 2, c0 = (t & 3) * 64;
    const u16* src = ctx + ((size_t)(b * 512 + l0 + tok)) * 256 + c0;
#pragma unroll
    for (int i = 0; i < 8; ++i)
      *(bf16x8*)&CT[tok * 264 + c0 + i * 8] = *(const bf16x8*)&src[i * 8];
  }
  for (int i = 0; i < 64; ++i) { int e = t + i * 256; FCT[(e & 63) * 264 + (e >> 6)] = (short)f2bf(fcw[e]); }
  for (int i = 0; i < 16; ++i) { int e = t + i * 256; F1T[(e & 63) * 72 + (e >> 6)] = (short)f2bf(f1w[e]); }
  for (int i = 0; i < 16; ++i) { int e = t + i * 256; F2T[(e & 63) * 72 + (e >> 6)] = (short)f2bf(f2w[e]); }
  __syncthreads();

  int w = t >> 6, lane = t & 63, lrow = lane & 15, lgrp = lane >> 4;
  int row = w * 16 + lgrp * 4;
  const f32x4 fz = {0.f, 0.f, 0.f, 0.f};

  f32x4 acc[4];
#pragma unroll
  for (int nt = 0; nt < 4; ++nt) acc[nt] = fz;
#pragma unroll
  for (int ks = 0; ks < 8; ++ks) {
    bf16x8 a = *(const bf16x8*)&CT[(w * 16 + lrow) * 264 + ks * 32 + lgrp * 8];
#pragma unroll
    for (int nt = 0; nt < 4; ++nt)
      acc[nt] = mfma16(a, *(const bf16x8*)&FCT[(nt * 16 + lrow) * 264 + ks * 32 + lgrp * 8], acc[nt]);
  }
  const float* xb = x + ((size_t)(b * 512 + l0)) * 64;
#pragma unroll
  for (int nt = 0; nt < 4; ++nt)
#pragma unroll
    for (int j = 0; j < 4; ++j)
      acc[nt][j] += xb[(row + j) * 64 + nt * 16 + lrow];

  float mean[4], rstd[4];
#pragma unroll
  for (int j = 0; j < 4; ++j) {
    float s = acc[0][j] + acc[1][j] + acc[2][j] + acc[3][j];
    s += __shfl_xor(s, 1); s += __shfl_xor(s, 2); s += __shfl_xor(s, 4); s += __shfl_xor(s, 8);
    mean[j] = s * 0.015625f;
  }
#pragma unroll
  for (int j = 0; j < 4; ++j) {
    float d0 = acc[0][j] - mean[j], d1 = acc[1][j] - mean[j];
    float d2 = acc[2][j] - mean[j], d3 = acc[3][j] - mean[j];
    float s = d0 * d0 + d1 * d1 + d2 * d2 + d3 * d3;
    s += __shfl_xor(s, 1); s += __shfl_xor(s, 2); s += __shfl_xor(s, 4); s += __shfl_xor(s, 8);
    rstd[j] = 1.0f / sqrtf(s * 0.015625f + 1e-5f);
  }
#pragma unroll
  for (int nt = 0; nt < 4; ++nt)
#pragma unroll
    for (int j = 0; j < 4; ++j) {
      float v = (acc[nt][j] - mean[j]) * rstd[j];
      ENC[(row + j) * 68 + nt * 16 + lrow] = v;
      EBF[(row + j) * 72 + nt * 16 + lrow] = (short)f2bf(v);
    }

  f32x4 h4[4];
#pragma unroll
  for (int nt = 0; nt < 4; ++nt) h4[nt] = fz;
#pragma unroll
  for (int ks = 0; ks < 2; ++ks) {
    bf16x8 a = *(const bf16x8*)&EBF[(w * 16 + lrow) * 72 + ks * 32 + lgrp * 8];
#pragma unroll
    for (int nt = 0; nt < 4; ++nt)
      h4[nt] = mfma16(a, *(const bf16x8*)&F1T[(nt * 16 + lrow) * 72 + ks * 32 + lgrp * 8], h4[nt]);
  }
#pragma unroll
  for (int nt = 0; nt < 4; ++nt)
#pragma unroll
    for (int j = 0; j < 4; ++j)
      HBF[(row + j) * 72 + nt * 16 + lrow] = (short)f2bf(fmaxf(h4[nt][j], 0.f));

  f32x4 o4[4];
#pragma unroll
  for (int nt = 0; nt < 4; ++nt) o4[nt] = fz;
#pragma unroll
  for (int ks = 0; ks < 2; ++ks) {
    bf16x8 a = *(const bf16x8*)&HBF[(w * 16 + lrow) * 72 + ks * 32 + lgrp * 8];
#pragma unroll
    for (int nt = 0; nt < 4; ++nt)
      o4[nt] = mfma16(a, *(const bf16x8*)&F2T[(nt * 16 + lrow) * 72 + ks * 32 + lgrp * 8], o4[nt]);
  }
#pragma unroll
  for (int nt = 0; nt < 4; ++nt)
#pragma unroll
    for (int j = 0; j < 4; ++j)
      o4[nt][j] += ENC[(row + j) * 68 + nt * 16 + lrow];

  float mean2[4], rstd2[4];
#pragma unroll
  for (int j = 0; j < 4; ++j) {
    float s = o4[0][j] + o4[1][j] + o4[2][j] + o4[3][j];
    s += __shfl_xor(s, 1); s += __shfl_xor(s, 2); s += __shfl_xor(s, 4); s += __shfl_xor(s, 8);
    mean2[j] = s * 0.015625f;
  }
#pragma unroll
  for (int j = 0; j < 4; ++j) {
    float d0 = o4[0][j] - mean2[j], d1 = o4[1][j] - mean2[j];
    float d2 = o4[2][j] - mean2[j], d3 = o4[3][j] - mean2[j];
    float s = d0 * d0 + d1 * d1 + d2 * d2 + d3 * d3;
    s += __shfl_xor(s, 1); s += __shfl_xor(s, 2); s += __shfl_xor(s, 4); s += __shfl_xor(s, 8);
    rstd2[j] = 1.0f / sqrtf(s * 0.015625f + 1e-5f);
  }
#pragma unroll
  for (int nt = 0; nt < 4; ++nt)
#pragma unroll
    for (int j = 0; j < 4; ++j)
      out[((size_t)(b * 512 + l0) + row + j) * 64 + nt * 16 + lrow] =
          (o4[nt][j] - mean2[j]) * rstd2[j];
}

// ---------------- launch ----------------
extern "C" void kernel_launch(void* const* d_in, const int* in_sizes, int n_in,
                              void* d_out, int out_size, void* d_ws, size_t ws_size,
                              hipStream_t stream) {
  const float* x   = (const float*)d_in[0];
  const void*  msk = d_in[1];
  const float* iu  = (const float*)d_in[2];
  const float* wq  = (const float*)d_in[3];
  const float* wk  = (const float*)d_in[4];
  const float* wv  = (const float*)d_in[5];
  const float* uq  = (const float*)d_in[6];
  const float* uk  = (const float*)d_in[7];
  const float* uv  = (const float*)d_in[8];
  const float* q1  = (const float*)d_in[9];
  const float* q2  = (const float*)d_in[10];
  const float* k1  = (const float*)d_in[11];
  const float* k2  = (const float*)d_in[12];
  const float* v1  = (const float*)d_in[13];
  const float* v2  = (const float*)d_in[14];
  const float* fcw = (const float*)d_in[15];
  const float* f1w = (const float*)d_in[16];
  const float* f2w = (const float*)d_in[17];
  float* out = (float*)d_out;

  char* ws = (char*)d_ws;
  u32*   flags = (u32*)ws;
  float* gates = (float*)(ws + 64);
  u16* qc  = (u16*)(ws + 4096);
  u16* qu  = (u16*)(ws + 33558528);
  u16* kc  = (u16*)(ws + 41947136);
  u16* ku  = (u16*)(ws + 75501568);
  u16* vpt = (u16*)(ws + 83890176);
  u8*  mb  = (u8*) (ws + 117444608);
  u16* ctx = (u16*)(ws + 150999040);

  kflaginit<<<dim3(1), dim3(1), 0, stream>>>(flags);
  kscan<<<dim3(1024), dim3(256), 0, stream>>>((const u32*)msk, flags);
  kconv<<<dim3(32768), dim3(256), 0, stream>>>(msk, flags, mb);
  kgates<<<dim3(128), dim3(64), 0, stream>>>(iu, q1, q2, k1, k2, v1, v2, gates);
  kproj_qk<<<dim3(1024), dim3(256), 0, stream>>>(x, wq, uq, wk, uk, gates, qc, qu, kc, ku);
  kproj_v<<<dim3(1024), dim3(256), 0, stream>>>(x, wv, uv, gates, vpt);
  kattn<<<dim3(4096), dim3(256), 0, stream>>>(qc, qu, kc, ku, vpt, mb, out + 4194304, ctx);
  kffn<<<dim3(1024), dim3(256), 0, stream>>>(ctx, x, fcw, f1w, f2w, out);
}

// Round 2
// 463.726 us; speedup vs baseline: 1.1604x; 1.1604x over previous
//
#include <hip/hip_runtime.h>

typedef unsigned char  u8;
typedef unsigned short u16;
typedef unsigned int   u32;

typedef __attribute__((ext_vector_type(8))) short bf16x8;
typedef __attribute__((ext_vector_type(4))) float f32x4;

__device__ __forceinline__ u16 f2bf(float f) {
  union { float f; u32 u; } v; v.f = f;
  u32 u = v.u;
  u32 r = u + 0x7fffu + ((u >> 16) & 1u);
  return (u16)(r >> 16);
}
__device__ __forceinline__ float bf2f(u16 h) {
  union { u32 u; float f; } v; v.u = ((u32)h) << 16;
  return v.f;
}
__device__ __forceinline__ bf16x8 pack8(float4 a, float4 b) {
  bf16x8 r;
  r[0] = (short)f2bf(a.x); r[1] = (short)f2bf(a.y);
  r[2] = (short)f2bf(a.z); r[3] = (short)f2bf(a.w);
  r[4] = (short)f2bf(b.x); r[5] = (short)f2bf(b.y);
  r[6] = (short)f2bf(b.z); r[7] = (short)f2bf(b.w);
  return r;
}
__device__ __forceinline__ f32x4 mfma16(bf16x8 a, bf16x8 b, f32x4 c) {
  return __builtin_amdgcn_mfma_f32_16x16x32_bf16(a, b, c, 0, 0, 0);
}

// ---------------- mask dtype detection + conversion ----------------
__global__ void kflaginit(u32* flags) { flags[0] = 0; flags[1] = 0; }

__global__ void kscan(const u32* __restrict__ m, u32* __restrict__ flags) {
  int gid = blockIdx.x * 256 + threadIdx.x;
  const uint4* p = (const uint4*)m;
  u32 gt = 0, fp = 0;
#pragma unroll
  for (int i = 0; i < 4; ++i) {
    uint4 v = p[gid * 4 + i];
    gt |= (u32)((v.x > 1u) | (v.y > 1u) | (v.z > 1u) | (v.w > 1u));
    fp |= (u32)((v.x == 0x3F800000u) | (v.y == 0x3F800000u) |
                (v.z == 0x3F800000u) | (v.w == 0x3F800000u));
  }
  if (gt) flags[0] = 1;
  if (fp) flags[1] = 1;
}

__global__ void kconv(const void* __restrict__ m, const u32* __restrict__ flags,
                      u8* __restrict__ out) {
  int gid = blockIdx.x * 256 + threadIdx.x;
  u32 isf = flags[1], isb = flags[0];
  uchar4 o;
  if (isf) {
    float4 v = ((const float4*)m)[gid];
    o.x = v.x != 0.f; o.y = v.y != 0.f; o.z = v.z != 0.f; o.w = v.w != 0.f;
  } else if (isb) {
    uchar4 v = ((const uchar4*)m)[gid];
    o.x = v.x != 0; o.y = v.y != 0; o.z = v.z != 0; o.w = v.w != 0;
  } else {
    uint4 v = ((const uint4*)m)[gid];
    o.x = v.x != 0; o.y = v.y != 0; o.z = v.z != 0; o.w = v.w != 0;
  }
  ((uchar4*)out)[gid] = o;
}

// ---------------- per-batch scalar gates ----------------
__global__ void kgates(const float* __restrict__ iu,
                       const float* __restrict__ q1, const float* __restrict__ q2,
                       const float* __restrict__ k1, const float* __restrict__ k2,
                       const float* __restrict__ v1, const float* __restrict__ v2,
                       float* __restrict__ gates) {
  int b = blockIdx.x, t = threadIdx.x;
  __shared__ float u[64];
  u[t] = iu[b * 64 + t];
  __syncthreads();
  const float* w1[3] = {q1, k1, v1};
  const float* w2[3] = {q2, k2, v2};
#pragma unroll
  for (int m = 0; m < 3; ++m) {
    float p = 0.f;
    if (t < 32) {
      float h = 0.f;
      for (int i = 0; i < 64; ++i) h += u[i] * w1[m][i * 32 + t];
      h = fmaxf(h, 0.f);
      p = h * w2[m][t];
    }
    for (int off = 32; off >= 1; off >>= 1) p += __shfl_xor(p, off);
    if (t == 0) gates[m * 128 + b] = p;
  }
}

// ---------------- Q/K projections (scale folded; u-parts shared) ----------------
__launch_bounds__(256, 1)
__global__ void kproj_qk(const float* __restrict__ x,
                         const float* __restrict__ wq, const float* __restrict__ uq,
                         const float* __restrict__ wk, const float* __restrict__ uk,
                         const float* __restrict__ gates,
                         u16* __restrict__ qc, u16* __restrict__ qu,
                         u16* __restrict__ kc, u16* __restrict__ ku) {
  __shared__ u16 XT[64 * 136];
  __shared__ u16 WT[640 * 72];
  int b = blockIdx.x >> 3, l0 = (blockIdx.x & 7) * 64, t = threadIdx.x;
  {
    int tok = t >> 2, i0 = (t & 3) * 16;
    const float4* s = (const float4*)(x + ((size_t)(b * 512 + l0 + tok)) * 64 + i0);
    *(bf16x8*)&XT[tok * 136 + i0]     = pack8(s[0], s[1]);
    *(bf16x8*)&XT[tok * 136 + i0 + 8] = pack8(s[2], s[3]);
  }
  for (int i = 0; i < 64; ++i) { int e = t + i * 256; WT[(e & 255) * 72 + (e >> 8)] = (short)f2bf(wq[e]); }
  for (int i = 0; i < 16; ++i) { int e = t + i * 256; WT[(256 + (e & 63)) * 72 + (e >> 6)] = (short)f2bf(uq[e]); }
  for (int i = 0; i < 64; ++i) { int e = t + i * 256; WT[(320 + (e & 255)) * 72 + (e >> 8)] = (short)f2bf(wk[e]); }
  for (int i = 0; i < 16; ++i) { int e = t + i * 256; WT[(576 + (e & 63)) * 72 + (e >> 6)] = (short)f2bf(uk[e]); }
  __syncthreads();

  int w = t >> 6, lane = t & 63, lrow = lane & 15, lgrp = lane >> 4;
  bf16x8 af[4][2];
#pragma unroll
  for (int m = 0; m < 4; ++m)
#pragma unroll
    for (int fs = 0; fs < 2; ++fs)
      af[m][fs] = *(const bf16x8*)&XT[(m * 16 + lrow) * 136 + fs * 32 + lgrp * 8];

  float sq = gates[b], sk = gates[128 + b];
  const f32x4 fz = {0.f, 0.f, 0.f, 0.f};
#pragma unroll
  for (int part = 0; part < 2; ++part) {
    f32x4 acc[4][5];
#pragma unroll
    for (int m = 0; m < 4; ++m)
#pragma unroll
      for (int nt = 0; nt < 5; ++nt) acc[m][nt] = fz;
#pragma unroll
    for (int fs = 0; fs < 2; ++fs)
#pragma unroll
      for (int nt = 0; nt < 5; ++nt) {
        bf16x8 bf = *(const bf16x8*)&WT[(part * 320 + w * 80 + nt * 16 + lrow) * 72 + fs * 32 + lgrp * 8];
#pragma unroll
        for (int m = 0; m < 4; ++m)
          acc[m][nt] = mfma16(af[m][fs], bf, acc[m][nt]);
      }
    u16* dstC = part ? kc : qc;
    u16* dstU = part ? ku : qu;
    float presc = part ? 1.0f : 0.125f;
    float g = (part ? sk : sq) * presc;
#pragma unroll
    for (int nt = 0; nt < 5; ++nt) {
      int ncol = w * 80 + nt * 16 + lrow;
#pragma unroll
      for (int m = 0; m < 4; ++m)
#pragma unroll
        for (int j = 0; j < 4; ++j) {
          int l = l0 + m * 16 + lgrp * 4 + j;
          float v = acc[m][nt][j];
          if (ncol < 256) {
            dstC[(((size_t)(b * 4 + (ncol >> 6)) * 512) + l) * 64 + (ncol & 63)] = (short)f2bf(v * presc);
          } else {
            dstU[((size_t)b * 512 + l) * 64 + (ncol - 256)] = (short)f2bf(v * g);
          }
        }
    }
  }
}

// ---------------- V projection, gated u_V add, transposed store ----------------
__launch_bounds__(256, 1)
__global__ void kproj_v(const float* __restrict__ x,
                        const float* __restrict__ wv, const float* __restrict__ uv,
                        const float* __restrict__ gates, u16* __restrict__ vpt) {
  __shared__ u16 XT[64 * 136];
  __shared__ u16 WT[320 * 72];
  __shared__ float Vs[64 * 328];
  int b = blockIdx.x >> 3, l0 = (blockIdx.x & 7) * 64, t = threadIdx.x;
  {
    int tok = t >> 2, i0 = (t & 3) * 16;
    const float4* s = (const float4*)(x + ((size_t)(b * 512 + l0 + tok)) * 64 + i0);
    *(bf16x8*)&XT[tok * 136 + i0]     = pack8(s[0], s[1]);
    *(bf16x8*)&XT[tok * 136 + i0 + 8] = pack8(s[2], s[3]);
  }
  for (int i = 0; i < 64; ++i) { int e = t + i * 256; WT[(e & 255) * 72 + (e >> 8)] = (short)f2bf(wv[e]); }
  for (int i = 0; i < 16; ++i) { int e = t + i * 256; WT[(256 + (e & 63)) * 72 + (e >> 6)] = (short)f2bf(uv[e]); }
  __syncthreads();

  int w = t >> 6, lane = t & 63, lrow = lane & 15, lgrp = lane >> 4;
  bf16x8 af[4][2];
#pragma unroll
  for (int m = 0; m < 4; ++m)
#pragma unroll
    for (int fs = 0; fs < 2; ++fs)
      af[m][fs] = *(const bf16x8*)&XT[(m * 16 + lrow) * 136 + fs * 32 + lgrp * 8];

  const f32x4 fz = {0.f, 0.f, 0.f, 0.f};
  f32x4 acc[4][5];
#pragma unroll
  for (int m = 0; m < 4; ++m)
#pragma unroll
    for (int nt = 0; nt < 5; ++nt) acc[m][nt] = fz;
#pragma unroll
  for (int fs = 0; fs < 2; ++fs)
#pragma unroll
    for (int nt = 0; nt < 5; ++nt) {
      bf16x8 bf = *(const bf16x8*)&WT[(w * 80 + nt * 16 + lrow) * 72 + fs * 32 + lgrp * 8];
#pragma unroll
      for (int m = 0; m < 4; ++m)
        acc[m][nt] = mfma16(af[m][fs], bf, acc[m][nt]);
    }
#pragma unroll
  for (int nt = 0; nt < 5; ++nt)
#pragma unroll
    for (int m = 0; m < 4; ++m)
#pragma unroll
      for (int j = 0; j < 4; ++j)
        Vs[(m * 16 + lgrp * 4 + j) * 328 + w * 80 + nt * 16 + lrow] = acc[m][nt][j];
  __syncthreads();

  float sv = gates[256 + b];
#pragma unroll
  for (int p = 0; p < 4; ++p) {
    int hd = p * 64 + (t >> 2);
    int d = hd & 63;
    int tok0 = (t & 3) * 16;
    bf16x8 v0, v1;
#pragma unroll
    for (int i = 0; i < 8; ++i) {
      int tok = tok0 + i;
      v0[i] = (short)f2bf(Vs[tok * 328 + hd] + Vs[tok * 328 + 256 + d] * sv);
    }
#pragma unroll
    for (int i = 0; i < 8; ++i) {
      int tok = tok0 + 8 + i;
      v1[i] = (short)f2bf(Vs[tok * 328 + hd] + Vs[tok * 328 + 256 + d] * sv);
    }
    size_t base = (((size_t)(b * 4 + (hd >> 6)) * 64) + d) * 512 + l0 + tok0;
    *(bf16x8*)&vpt[base] = v0;
    *(bf16x8*)&vpt[base + 8] = v1;
  }
}

// ---------------- fused attention: 8 waves, (qsub, k/d-group) split ----------------
__launch_bounds__(512, 4)
__global__ void kattn(const u16* __restrict__ qc, const u16* __restrict__ qu,
                      const u16* __restrict__ kc, const u16* __restrict__ ku,
                      const u16* __restrict__ vpt, const u8* __restrict__ maskb,
                      float* __restrict__ aout, u16* __restrict__ ctx) {
  __shared__ char smem[53248];
  u16* QT = (u16*)smem;                      // phase1 [64][136]
  u16* KT = (u16*)(smem + 17408);            // phase1 [128][136]
  float* SMm = (float*)(smem + 52224);       // [128]
  float* SMl = (float*)(smem + 52736);       // [128]
  u16* Vt = (u16*)smem;                      // phase2 chunk [64 d][136]
  u16* Pl = (u16*)(smem + 17408);            // phase2 chunk [64 q][136]

  // XCD-aware swizzle: contiguous chunk per XCD; within: b outer, qt, h inner
  int bid = blockIdx.x;
  int logical = (bid & 7) * 512 + (bid >> 3);
  int b = logical >> 5;
  int r5 = logical & 31;
  int qt = r5 >> 2, hh = r5 & 3;
  int bh = b * 4 + hh;
  int q0 = qt * 64;

  int t = threadIdx.x, w = t >> 6, lane = t & 63, lrow = lane & 15, lgrp = lane >> 4;
  int qsub = w & 3, g = w >> 2, g64 = g * 64;

  { // stage Q tile [64][128]: cols 0-63 = Q(head), 64-127 = uQ(shared)
    int tok = t >> 3, c0 = (t & 7) * 16;
    const u16* src = (c0 < 64)
      ? qc + ((size_t)bh * 512 + q0 + tok) * 64 + c0
      : qu + ((size_t)b  * 512 + q0 + tok) * 64 + (c0 - 64);
    *(bf16x8*)&QT[tok * 136 + c0]     = *(const bf16x8*)&src[0];
    *(bf16x8*)&QT[tok * 136 + c0 + 8] = *(const bf16x8*)&src[8];
  }

  const f32x4 fz = {0.f, 0.f, 0.f, 0.f};
  f32x4 acc[16];
#pragma unroll
  for (int i = 0; i < 16; ++i) acc[i] = fz;

#pragma unroll
  for (int kt = 0; kt < 4; ++kt) {
    __syncthreads();
    { // stage K rows kt*128..+128: cols 0-63 = K, 64-127 = uK
      int r = t >> 2, c0 = (t & 3) * 32;
      const u16* src = (c0 < 64)
        ? kc + ((size_t)bh * 512 + kt * 128 + r) * 64 + c0
        : ku + ((size_t)b  * 512 + kt * 128 + r) * 64 + (c0 - 64);
#pragma unroll
      for (int i = 0; i < 4; ++i)
        *(bf16x8*)&KT[r * 136 + c0 + i * 8] = *(const bf16x8*)&src[i * 8];
    }
    __syncthreads();
#pragma unroll
    for (int fs = 0; fs < 4; ++fs) {
      bf16x8 a = *(const bf16x8*)&QT[(qsub * 16 + lrow) * 136 + fs * 32 + lgrp * 8];
#pragma unroll
      for (int nt = 0; nt < 4; ++nt) {
        bf16x8 bf = *(const bf16x8*)&KT[(g64 + nt * 16 + lrow) * 136 + fs * 32 + lgrp * 8];
        acc[kt * 4 + nt] = mfma16(a, bf, acc[kt * 4 + nt]);
      }
    }
  }

  // mask + two-group exact softmax
  int qloc0 = qsub * 16 + lgrp * 4;
  const u8* mrow = maskb + ((size_t)b * 512 + q0 + qloc0) * 512;
  float mj[4] = {-3.0e38f, -3.0e38f, -3.0e38f, -3.0e38f};
#pragma unroll
  for (int i = 0; i < 16; ++i) {
    int kpos = (i >> 2) * 128 + g64 + (i & 3) * 16 + lrow;
#pragma unroll
    for (int j = 0; j < 4; ++j) {
      float s = acc[i][j];
      if (mrow[(size_t)j * 512 + kpos]) s = -1.0e9f;
      acc[i][j] = s;
      mj[j] = fmaxf(mj[j], s);
    }
  }
#pragma unroll
  for (int j = 0; j < 4; ++j) {
    mj[j] = fmaxf(mj[j], __shfl_xor(mj[j], 1));
    mj[j] = fmaxf(mj[j], __shfl_xor(mj[j], 2));
    mj[j] = fmaxf(mj[j], __shfl_xor(mj[j], 4));
    mj[j] = fmaxf(mj[j], __shfl_xor(mj[j], 8));
  }
  if (lrow == 0) {
#pragma unroll
    for (int j = 0; j < 4; ++j) SMm[g64 + qloc0 + j] = mj[j];
  }
  __syncthreads();
  float gm[4];
#pragma unroll
  for (int j = 0; j < 4; ++j) gm[j] = fmaxf(SMm[qloc0 + j], SMm[64 + qloc0 + j]);
  float lj[4] = {0.f, 0.f, 0.f, 0.f};
#pragma unroll
  for (int i = 0; i < 16; ++i)
#pragma unroll
    for (int j = 0; j < 4; ++j) {
      float p = __expf(acc[i][j] - gm[j]);
      acc[i][j] = p;
      lj[j] += p;
    }
#pragma unroll
  for (int j = 0; j < 4; ++j) {
    lj[j] += __shfl_xor(lj[j], 1);
    lj[j] += __shfl_xor(lj[j], 2);
    lj[j] += __shfl_xor(lj[j], 4);
    lj[j] += __shfl_xor(lj[j], 8);
  }
  if (lrow == 0) {
#pragma unroll
    for (int j = 0; j < 4; ++j) SMl[g64 + qloc0 + j] = lj[j];
  }
  __syncthreads();
  float inv[4];
#pragma unroll
  for (int j = 0; j < 4; ++j) inv[j] = 1.0f / (SMl[qloc0 + j] + SMl[64 + qloc0 + j]);

  // normalize in-register + write attn
  size_t ab = ((size_t)bh * 512 + q0 + qloc0) * 512;
#pragma unroll
  for (int i = 0; i < 16; ++i) {
    int kpos = (i >> 2) * 128 + g64 + (i & 3) * 16 + lrow;
#pragma unroll
    for (int j = 0; j < 4; ++j) {
      float av = acc[i][j] * inv[j];
      acc[i][j] = av;
      aout[ab + (size_t)j * 512 + kpos] = av;
    }
  }

  // phase 2: context = P @ Vp in 4 k-chunks of 128; all 8 waves MFMA (split by d-half)
  f32x4 cacc[2] = {fz, fz};
#pragma unroll
  for (int c = 0; c < 4; ++c) {
    { // stage Vp^T chunk [64 d][128 k]
      int d = t >> 3, c0 = (t & 7) * 16;
      const u16* src = vpt + ((size_t)bh * 64 + d) * 512 + c * 128 + c0;
      *(bf16x8*)&Vt[d * 136 + c0]     = *(const bf16x8*)&src[0];
      *(bf16x8*)&Vt[d * 136 + c0 + 8] = *(const bf16x8*)&src[8];
    }
    // drop this wave's P columns for the chunk into LDS
#pragma unroll
    for (int nt = 0; nt < 4; ++nt)
#pragma unroll
      for (int j = 0; j < 4; ++j)
        Pl[(qloc0 + j) * 136 + g64 + nt * 16 + lrow] = (short)f2bf(acc[c * 4 + nt][j]);
    __syncthreads();
#pragma unroll
    for (int ks = 0; ks < 4; ++ks) {
      bf16x8 a = *(const bf16x8*)&Pl[(qsub * 16 + lrow) * 136 + ks * 32 + lgrp * 8];
#pragma unroll
      for (int nt2 = 0; nt2 < 2; ++nt2) {
        bf16x8 bf = *(const bf16x8*)&Vt[(g * 32 + nt2 * 16 + lrow) * 136 + ks * 32 + lgrp * 8];
        cacc[nt2] = mfma16(a, bf, cacc[nt2]);
      }
    }
    __syncthreads();
  }
#pragma unroll
  for (int nt2 = 0; nt2 < 2; ++nt2)
#pragma unroll
    for (int j = 0; j < 4; ++j)
      ctx[((size_t)b * 512 + q0 + qloc0 + j) * 256 + hh * 64 + g * 32 + nt2 * 16 + lrow] =
          (short)f2bf(cacc[nt2][j]);
}

// ---------------- fc + residual + LN + FFN + residual + LN ----------------
__launch_bounds__(256, 1)
__global__ void kffn(const u16* __restrict__ ctx, const float* __restrict__ x,
                     const float* __restrict__ fcw, const float* __restrict__ f1w,
                     const float* __restrict__ f2w, float* __restrict__ out) {
  __shared__ u16 CT[64 * 264];
  __shared__ u16 FCT[64 * 264];
  __shared__ u16 F1T[64 * 72];
  __shared__ u16 F2T[64 * 72];
  __shared__ float ENC[64 * 68];
  __shared__ u16 EBF[64 * 72];
  __shared__ u16 HBF[64 * 72];
  int b = blockIdx.x >> 3, l0 = (blockIdx.x & 7) * 64, t = threadIdx.x;
  {
    int tok = t >> 2, c0 = (t & 3) * 64;
    const u16* src = ctx + ((size_t)(b * 512 + l0 + tok)) * 256 + c0;
#pragma unroll
    for (int i = 0; i < 8; ++i)
      *(bf16x8*)&CT[tok * 264 + c0 + i * 8] = *(const bf16x8*)&src[i * 8];
  }
  for (int i = 0; i < 64; ++i) { int e = t + i * 256; FCT[(e & 63) * 264 + (e >> 6)] = (short)f2bf(fcw[e]); }
  for (int i = 0; i < 16; ++i) { int e = t + i * 256; F1T[(e & 63) * 72 + (e >> 6)] = (short)f2bf(f1w[e]); }
  for (int i = 0; i < 16; ++i) { int e = t + i * 256; F2T[(e & 63) * 72 + (e >> 6)] = (short)f2bf(f2w[e]); }
  __syncthreads();

  int w = t >> 6, lane = t & 63, lrow = lane & 15, lgrp = lane >> 4;
  int row = w * 16 + lgrp * 4;
  const f32x4 fz = {0.f, 0.f, 0.f, 0.f};

  f32x4 acc[4];
#pragma unroll
  for (int nt = 0; nt < 4; ++nt) acc[nt] = fz;
#pragma unroll
  for (int ks = 0; ks < 8; ++ks) {
    bf16x8 a = *(const bf16x8*)&CT[(w * 16 + lrow) * 264 + ks * 32 + lgrp * 8];
#pragma unroll
    for (int nt = 0; nt < 4; ++nt)
      acc[nt] = mfma16(a, *(const bf16x8*)&FCT[(nt * 16 + lrow) * 264 + ks * 32 + lgrp * 8], acc[nt]);
  }
  const float* xb = x + ((size_t)(b * 512 + l0)) * 64;
#pragma unroll
  for (int nt = 0; nt < 4; ++nt)
#pragma unroll
    for (int j = 0; j < 4; ++j)
      acc[nt][j] += xb[(row + j) * 64 + nt * 16 + lrow];

  float mean[4], rstd[4];
#pragma unroll
  for (int j = 0; j < 4; ++j) {
    float s = acc[0][j] + acc[1][j] + acc[2][j] + acc[3][j];
    s += __shfl_xor(s, 1); s += __shfl_xor(s, 2); s += __shfl_xor(s, 4); s += __shfl_xor(s, 8);
    mean[j] = s * 0.015625f;
  }
#pragma unroll
  for (int j = 0; j < 4; ++j) {
    float d0 = acc[0][j] - mean[j], d1 = acc[1][j] - mean[j];
    float d2 = acc[2][j] - mean[j], d3 = acc[3][j] - mean[j];
    float s = d0 * d0 + d1 * d1 + d2 * d2 + d3 * d3;
    s += __shfl_xor(s, 1); s += __shfl_xor(s, 2); s += __shfl_xor(s, 4); s += __shfl_xor(s, 8);
    rstd[j] = 1.0f / sqrtf(s * 0.015625f + 1e-5f);
  }
#pragma unroll
  for (int nt = 0; nt < 4; ++nt)
#pragma unroll
    for (int j = 0; j < 4; ++j) {
      float v = (acc[nt][j] - mean[j]) * rstd[j];
      ENC[(row + j) * 68 + nt * 16 + lrow] = v;
      EBF[(row + j) * 72 + nt * 16 + lrow] = (short)f2bf(v);
    }

  f32x4 h4[4];
#pragma unroll
  for (int nt = 0; nt < 4; ++nt) h4[nt] = fz;
#pragma unroll
  for (int ks = 0; ks < 2; ++ks) {
    bf16x8 a = *(const bf16x8*)&EBF[(w * 16 + lrow) * 72 + ks * 32 + lgrp * 8];
#pragma unroll
    for (int nt = 0; nt < 4; ++nt)
      h4[nt] = mfma16(a, *(const bf16x8*)&F1T[(nt * 16 + lrow) * 72 + ks * 32 + lgrp * 8], h4[nt]);
  }
#pragma unroll
  for (int nt = 0; nt < 4; ++nt)
#pragma unroll
    for (int j = 0; j < 4; ++j)
      HBF[(row + j) * 72 + nt * 16 + lrow] = (short)f2bf(fmaxf(h4[nt][j], 0.f));

  f32x4 o4[4];
#pragma unroll
  for (int nt = 0; nt < 4; ++nt) o4[nt] = fz;
#pragma unroll
  for (int ks = 0; ks < 2; ++ks) {
    bf16x8 a = *(const bf16x8*)&HBF[(w * 16 + lrow) * 72 + ks * 32 + lgrp * 8];
#pragma unroll
    for (int nt = 0; nt < 4; ++nt)
      o4[nt] = mfma16(a, *(const bf16x8*)&F2T[(nt * 16 + lrow) * 72 + ks * 32 + lgrp * 8], o4[nt]);
  }
#pragma unroll
  for (int nt = 0; nt < 4; ++nt)
#pragma unroll
    for (int j = 0; j < 4; ++j)
      o4[nt][j] += ENC[(row + j) * 68 + nt * 16 + lrow];

  float mean2[4], rstd2[4];
#pragma unroll
  for (int j = 0; j < 4; ++j) {
    float s = o4[0][j] + o4[1][j] + o4[2][j] + o4[3][j];
    s += __shfl_xor(s, 1); s += __shfl_xor(s, 2); s += __shfl_xor(s, 4); s += __shfl_xor(s, 8);
    mean2[j] = s * 0.015625f;
  }
#pragma unroll
  for (int j = 0; j < 4; ++j) {
    float d0 = o4[0][j] - mean2[j], d1 = o4[1][j] - mean2[j];
    float d2 = o4[2][j] - mean2[j], d3 = o4[3][j] - mean2[j];
    float s = d0 * d0 + d1 * d1 + d2 * d2 + d3 * d3;
    s += __shfl_xor(s, 1); s += __shfl_xor(s, 2); s += __shfl_xor(s, 4); s += __shfl_xor(s, 8);
    rstd2[j] = 1.0f / sqrtf(s * 0.015625f + 1e-5f);
  }
#pragma unroll
  for (int nt = 0; nt < 4; ++nt)
#pragma unroll
    for (int j = 0; j < 4; ++j)
      out[((size_t)(b * 512 + l0) + row + j) * 64 + nt * 16 + lrow] =
          (o4[nt][j] - mean2[j]) * rstd2[j];
}

// ---------------- launch ----------------
extern "C" void kernel_launch(void* const* d_in, const int* in_sizes, int n_in,
                              void* d_out, int out_size, void* d_ws, size_t ws_size,
                              hipStream_t stream) {
  const float* x   = (const float*)d_in[0];
  const void*  msk = d_in[1];
  const float* iu  = (const float*)d_in[2];
  const float* wq  = (const float*)d_in[3];
  const float* wk  = (const float*)d_in[4];
  const float* wv  = (const float*)d_in[5];
  const float* uq  = (const float*)d_in[6];
  const float* uk  = (const float*)d_in[7];
  const float* uv  = (const float*)d_in[8];
  const float* q1  = (const float*)d_in[9];
  const float* q2  = (const float*)d_in[10];
  const float* k1  = (const float*)d_in[11];
  const float* k2  = (const float*)d_in[12];
  const float* v1  = (const float*)d_in[13];
  const float* v2  = (const float*)d_in[14];
  const float* fcw = (const float*)d_in[15];
  const float* f1w = (const float*)d_in[16];
  const float* f2w = (const float*)d_in[17];
  float* out = (float*)d_out;

  char* ws = (char*)d_ws;
  u32*   flags = (u32*)ws;
  float* gates = (float*)(ws + 64);
  u16* qc  = (u16*)(ws + 4096);
  u16* qu  = (u16*)(ws + 33558528);
  u16* kc  = (u16*)(ws + 41947136);
  u16* ku  = (u16*)(ws + 75501568);
  u16* vpt = (u16*)(ws + 83890176);
  u8*  mb  = (u8*) (ws + 117444608);
  u16* ctx = (u16*)(ws + 150999040);

  kflaginit<<<dim3(1), dim3(1), 0, stream>>>(flags);
  kscan<<<dim3(1024), dim3(256), 0, stream>>>((const u32*)msk, flags);
  kconv<<<dim3(32768), dim3(256), 0, stream>>>(msk, flags, mb);
  kgates<<<dim3(128), dim3(64), 0, stream>>>(iu, q1, q2, k1, k2, v1, v2, gates);
  kproj_qk<<<dim3(1024), dim3(256), 0, stream>>>(x, wq, uq, wk, uk, gates, qc, qu, kc, ku);
  kproj_v<<<dim3(1024), dim3(256), 0, stream>>>(x, wv, uv, gates, vpt);
  kattn<<<dim3(4096), dim3(512), 0, stream>>>(qc, qu, kc, ku, vpt, mb, out + 4194304, ctx);
  kffn<<<dim3(1024), dim3(256), 0, stream>>>(ctx, x, fcw, f1w, f2w, out);
}